// Round 1
// baseline (837.028 us; speedup 1.0000x reference)
//
#include <hip/hip_runtime.h>
#include <hip/hip_bf16.h>

// AttributeGNN fused kernel, bf16 MFMA, fp32 accumulate.
// B=16384 batch, A=16 edge types, D=256 embedding.

typedef __bf16 bf16_t;
typedef __bf16 bf16x4 __attribute__((ext_vector_type(4)));
typedef __bf16 bf16x8 __attribute__((ext_vector_type(8)));
typedef float f32x4 __attribute__((ext_vector_type(4)));

#define NB 16384
#define NA 16
#define ND 256

// XOR swizzle for bf16 LDS tiles [32][256] (row stride 512B): flips byte bits 4-6
// with (row&7) -> in element (short) units that's bits 3-5. Keeps 16B/8B/4B chunks intact.
__device__ __forceinline__ int swz(int r, int c) {
    return r * 256 + (c ^ ((r & 7) << 3));
}

// One 32xK=256 x (64-col slice) bt-GEMM: A from swizzled LDS, B row-major [N][K] bf16 from global.
// acc layout per m89: col = lane&15, row = (lane>>4)*4 + j.
__device__ __forceinline__ void gemm_tile(const bf16_t* a_lds, const bf16_t* __restrict__ Bg,
                                          f32x4 acc[2][4], int lane, int n0w)
{
    const int lr = lane & 15, lhi = lane >> 4;
#pragma unroll
    for (int ks = 0; ks < 8; ++ks) {
        const int kc = ks * 32 + lhi * 8;
        bf16x8 af[2];
#pragma unroll
        for (int mi = 0; mi < 2; ++mi) {
            int r = mi * 16 + lr;
            af[mi] = *(const bf16x8*)&a_lds[swz(r, kc)];
        }
#pragma unroll
        for (int ni = 0; ni < 4; ++ni) {
            bf16x8 bfr = *(const bf16x8*)&Bg[(n0w + ni * 16 + lr) * 256 + kc];
#pragma unroll
            for (int mi = 0; mi < 2; ++mi)
                acc[mi][ni] = __builtin_amdgcn_mfma_f32_16x16x32_bf16(af[mi], bfr, acc[mi][ni], 0, 0, 0);
        }
    }
}

// W_agg [D][2D] fp32 -> W1 [D][D] bf16 (k-major), W2 [D][D] bf16.
__global__ void prep_w(const float* __restrict__ W, bf16_t* __restrict__ W1, bf16_t* __restrict__ W2)
{
    int o = blockIdx.x;
    int k = threadIdx.x;
    W1[o * 256 + k] = (bf16_t)W[o * 512 + k];
    W2[o * 256 + k] = (bf16_t)W[o * 512 + 256 + k];
}

// P[a][i][j] fp32 -> Pt[a][j][i] bf16 via LDS 32x32 tile transpose.
__global__ void transpose_P(const float* __restrict__ Pf, const float* __restrict__ Pb,
                            bf16_t* __restrict__ Pft, bf16_t* __restrict__ Pbt)
{
    __shared__ float t[32][33];
    int blk = blockIdx.x;
    int mat = blk >> 10;          // 1024 blocks per matrix (16 a * 64 tiles)
    int rest = blk & 1023;
    int a = rest >> 6;
    int tile = rest & 63;
    int i0 = (tile >> 3) * 32;
    int j0 = (tile & 7) * 32;
    const float* src = (mat ? Pb : Pf) + a * 65536;
    bf16_t* dst = (mat ? Pbt : Pft) + a * 65536;
    int r = threadIdx.x >> 5, c = threadIdx.x & 31;
#pragma unroll
    for (int it = 0; it < 4; ++it)
        t[r + 8 * it][c] = src[(i0 + r + 8 * it) * 256 + j0 + c];
    __syncthreads();
#pragma unroll
    for (int it = 0; it < 4; ++it)
        dst[(j0 + r + 8 * it) * 256 + i0 + c] = (bf16_t)t[c][r + 8 * it];
}

// T[b,o] = img[b,:] @ W1[o,:] + b_agg[o]   (a-invariant half of the concat Linear)
__global__ __launch_bounds__(256, 2)
void t_gemm(const float* __restrict__ img, const float* __restrict__ bias,
            const bf16_t* __restrict__ W1, float* __restrict__ Tg)
{
    __shared__ bf16_t i_lds[32 * 256];
    const int tid = threadIdx.x;
    const int lane = tid & 63;
    const int wave = tid >> 6;
    const int n0w = wave * 64;
    const int brow0 = blockIdx.x * 32;
    const int lr = lane & 15;
    const int lhi = lane >> 4;

    {
        const int rr = tid >> 6;
        const int c4 = (tid & 63) * 4;
#pragma unroll
        for (int it = 0; it < 8; ++it) {
            int r = rr + it * 4;
            f32x4 v = *(const f32x4*)&img[(size_t)(brow0 + r) * 256 + c4];
            bf16x4 s = { (bf16_t)v.x, (bf16_t)v.y, (bf16_t)v.z, (bf16_t)v.w };
            *(bf16x4*)&i_lds[swz(r, c4)] = s;
        }
    }
    __syncthreads();

    f32x4 acc[2][4];
#pragma unroll
    for (int ni = 0; ni < 4; ++ni) {
        float bz = bias[n0w + ni * 16 + lr];
#pragma unroll
        for (int mi = 0; mi < 2; ++mi)
#pragma unroll
            for (int j = 0; j < 4; ++j)
                acc[mi][ni][j] = bz;
    }
    gemm_tile(i_lds, W1, acc, lane, n0w);

#pragma unroll
    for (int mi = 0; mi < 2; ++mi)
#pragma unroll
        for (int ni = 0; ni < 4; ++ni)
#pragma unroll
            for (int j = 0; j < 4; ++j) {
                int r = mi * 16 + lhi * 4 + j;
                int c = n0w + ni * 16 + lr;
                Tg[(size_t)(brow0 + r) * 256 + c] = acc[mi][ni][j];
            }
}

// Fused per-(32-row block): loop a: stage edge->bf16 LDS, GEMM1 (+T init),
// GEMM2 -> attr out + LDS, GEMM3 -> relu -> indiv reg accumulate.
__global__ __launch_bounds__(256, 2)
void fused_main(const float* __restrict__ edge, const float* __restrict__ Tg,
                const bf16_t* __restrict__ W2, const bf16_t* __restrict__ Pf,
                const bf16_t* __restrict__ Pb, const float* __restrict__ sw,
                float* __restrict__ out)
{
    __shared__ float T_lds[32 * 256];   // 32 KB, a-invariant
    __shared__ bf16_t e_lds[32 * 256];  // 16 KB edge tile
    __shared__ bf16_t g_lds[32 * 256];  // 16 KB agg tile
    __shared__ bf16_t r_lds[32 * 256];  // 16 KB attr tile

    const int tid = threadIdx.x;
    const int lane = tid & 63;
    const int wave = tid >> 6;
    const int n0w = wave * 64;          // wave's 64-col slice of N=256
    const int brow0 = blockIdx.x * 32;
    const int lr = lane & 15;
    const int lhi = lane >> 4;

    // stage T tile once (fp32, no swizzle needed: 4B elements, consecutive cols)
    {
        const int rr = tid >> 6;
        const int c4 = (tid & 63) * 4;
#pragma unroll
        for (int it = 0; it < 8; ++it) {
            int r = rr + it * 4;
            *(f32x4*)&T_lds[r * 256 + c4] = *(const f32x4*)&Tg[(size_t)(brow0 + r) * 256 + c4];
        }
    }

    f32x4 indiv[2][4];
#pragma unroll
    for (int mi = 0; mi < 2; ++mi)
#pragma unroll
        for (int ni = 0; ni < 4; ++ni)
            indiv[mi][ni] = (f32x4){0.f, 0.f, 0.f, 0.f};

    f32x4 acc[2][4];

    for (int a = 0; a < NA; ++a) {
        // stage edge tile fp32 -> bf16, swizzled
        {
            const int rr = tid >> 6;
            const int c4 = (tid & 63) * 4;
#pragma unroll
            for (int it = 0; it < 8; ++it) {
                int r = rr + it * 4;
                f32x4 v = *(const f32x4*)&edge[(size_t)(brow0 + r) * 4096 + a * 256 + c4];
                bf16x4 s = { (bf16_t)v.x, (bf16_t)v.y, (bf16_t)v.z, (bf16_t)v.w };
                *(bf16x4*)&e_lds[swz(r, c4)] = s;
            }
        }
        __syncthreads();

        // GEMM1: agg = T + edge @ W2^T
#pragma unroll
        for (int mi = 0; mi < 2; ++mi)
#pragma unroll
            for (int ni = 0; ni < 4; ++ni)
#pragma unroll
                for (int j = 0; j < 4; ++j)
                    acc[mi][ni][j] = T_lds[(mi * 16 + lhi * 4 + j) * 256 + n0w + ni * 16 + lr];
        gemm_tile(e_lds, W2, acc, lane, n0w);

#pragma unroll
        for (int mi = 0; mi < 2; ++mi)
#pragma unroll
            for (int ni = 0; ni < 4; ++ni)
#pragma unroll
                for (int j = 0; j < 4; ++j) {
                    int r = mi * 16 + lhi * 4 + j;
                    int c = n0w + ni * 16 + lr;
                    g_lds[swz(r, c)] = (bf16_t)acc[mi][ni][j];
                }
        __syncthreads();

        // GEMM2: attr = agg @ P_fwd[a]
#pragma unroll
        for (int mi = 0; mi < 2; ++mi)
#pragma unroll
            for (int ni = 0; ni < 4; ++ni)
                acc[mi][ni] = (f32x4){0.f, 0.f, 0.f, 0.f};
        gemm_tile(g_lds, Pf + a * 65536, acc, lane, n0w);

#pragma unroll
        for (int mi = 0; mi < 2; ++mi)
#pragma unroll
            for (int ni = 0; ni < 4; ++ni)
#pragma unroll
                for (int j = 0; j < 4; ++j) {
                    int r = mi * 16 + lhi * 4 + j;
                    int c = n0w + ni * 16 + lr;
                    float v = acc[mi][ni][j];
                    out[(size_t)(brow0 + r) * 4096 + a * 256 + c] = v;  // attr output
                    r_lds[swz(r, c)] = (bf16_t)v;
                }
        __syncthreads();

        // GEMM3: proj = relu(attr @ P_bwd[a]); indiv += proj * sw[a]
#pragma unroll
        for (int mi = 0; mi < 2; ++mi)
#pragma unroll
            for (int ni = 0; ni < 4; ++ni)
                acc[mi][ni] = (f32x4){0.f, 0.f, 0.f, 0.f};
        gemm_tile(r_lds, Pb + a * 65536, acc, lane, n0w);

        const float swa = sw[a];
#pragma unroll
        for (int mi = 0; mi < 2; ++mi)
#pragma unroll
            for (int ni = 0; ni < 4; ++ni)
#pragma unroll
                for (int j = 0; j < 4; ++j)
                    indiv[mi][ni][j] += fmaxf(acc[mi][ni][j], 0.f) * swa;
        __syncthreads();
    }

    // write individual_embeddings
#pragma unroll
    for (int mi = 0; mi < 2; ++mi)
#pragma unroll
        for (int ni = 0; ni < 4; ++ni)
#pragma unroll
            for (int j = 0; j < 4; ++j) {
                int r = mi * 16 + lhi * 4 + j;
                int c = n0w + ni * 16 + lr;
                out[(size_t)NB * NA * ND + (size_t)(brow0 + r) * 256 + c] = indiv[mi][ni][j];
            }
}

extern "C" void kernel_launch(void* const* d_in, const int* in_sizes, int n_in,
                              void* d_out, int out_size, void* d_ws, size_t ws_size,
                              hipStream_t stream)
{
    const float* img  = (const float*)d_in[0];
    const float* edge = (const float*)d_in[1];
    const float* Wagg = (const float*)d_in[2];
    const float* bagg = (const float*)d_in[3];
    const float* Pf   = (const float*)d_in[4];
    const float* Pb   = (const float*)d_in[5];
    const float* sw   = (const float*)d_in[6];
    float* out = (float*)d_out;

    char* ws = (char*)d_ws;
    bf16_t* W1  = (bf16_t*)(ws);                        // 128 KB
    bf16_t* W2  = (bf16_t*)(ws + 131072);               // 128 KB
    bf16_t* Pft = (bf16_t*)(ws + 262144);               // 2 MB
    bf16_t* Pbt = (bf16_t*)(ws + 262144 + 2097152);     // 2 MB
    float*  Tg  = (float*)(ws + 262144 + 2 * 2097152);  // 16 MB

    prep_w<<<256, 256, 0, stream>>>(Wagg, W1, W2);
    transpose_P<<<2048, 256, 0, stream>>>(Pf, Pb, Pft, Pbt);
    t_gemm<<<512, 256, 0, stream>>>(img, bagg, W1, Tg);
    fused_main<<<512, 256, 0, stream>>>(edge, Tg, W2, Pft, Pbt, sw, out);
}